// Round 5
// baseline (614.556 us; speedup 1.0000x reference)
//
#include <hip/hip_runtime.h>
#include <math.h>

#define N_NODES 100000
#define N_EDGES 1600000
#define F_IN    500
#define HIDDEN  64
#define N_CLASS 40
#define KPAD    512

#define NB   2048      // dst buckets
#define NPB  49        // nodes per bucket (2048*49 = 100352 >= N)
#define EPB  16384     // edges per block in bhist/bfill
#define CAP  1536      // LDS pair capacity in k_bucket_csr (mean 781, 27 sigma)

typedef __attribute__((ext_vector_type(4))) float f32x4;
typedef __attribute__((ext_vector_type(8))) __bf16 bf16x8;

__device__ __forceinline__ unsigned short f2bf(float f) {
    unsigned int u = __float_as_uint(f);
    u = (u + 0x7FFF + ((u >> 16) & 1)) >> 16;   // RNE
    return (unsigned short)u;
}
__device__ __forceinline__ float bf2f(unsigned short u) {
    return __uint_as_float((unsigned int)u << 16);
}

// ---------- utility ----------
__global__ void k_zero_int(int* p, int n) {
    int i = blockIdx.x * blockDim.x + threadIdx.x;
    if (i < n) p[i] = 0;
}

// W1t[n][k] = bf16(W1[k][n]), k zero-padded to 512
__global__ void k_prep_w1t(const float* __restrict__ w1, unsigned short* __restrict__ w1t) {
    int idx = blockIdx.x * blockDim.x + threadIdx.x;
    if (idx >= HIDDEN * KPAD) return;
    int n = idx >> 9, k = idx & (KPAD - 1);
    float v = (k < F_IN) ? w1[k * HIDDEN + n] : 0.f;
    w1t[idx] = f2bf(v);
}

// ---------- CSR build: bucketed counting sort ----------
__launch_bounds__(1024)
__global__ void k_bhist(const int* __restrict__ dst, int* __restrict__ bcnt, int e) {
    __shared__ int h[NB];
    for (int i = threadIdx.x; i < NB; i += 1024) h[i] = 0;
    __syncthreads();
    int base = blockIdx.x * EPB;
#pragma unroll
    for (int j = 0; j < 16; ++j) {
        int i = base + j * 1024 + threadIdx.x;
        if (i < e) atomicAdd(&h[dst[i] / NPB], 1);
    }
    __syncthreads();
    for (int i = threadIdx.x; i < NB; i += 1024)
        if (h[i]) atomicAdd(&bcnt[i], h[i]);
}

__launch_bounds__(1024)
__global__ void k_bscan(const int* __restrict__ bcnt, int* __restrict__ bptr,
                        int* __restrict__ bcur) {
    __shared__ int s[1024];
    int t = threadIdx.x;
    int a = bcnt[2 * t], b = bcnt[2 * t + 1];
    int v = a + b;
    s[t] = v;
    __syncthreads();
    for (int off = 1; off < 1024; off <<= 1) {
        int u = (t >= off) ? s[t - off] : 0;
        __syncthreads();
        s[t] += u;
        __syncthreads();
    }
    int excl = s[t] - v;
    bptr[2 * t] = excl;     bptr[2 * t + 1] = excl + a;
    bcur[2 * t] = excl;     bcur[2 * t + 1] = excl + a;
    if (t == 1023) bptr[NB] = s[1023];
}

__launch_bounds__(1024)
__global__ void k_bfill(const int* __restrict__ src, const int* __restrict__ dst,
                        int* __restrict__ bcur, int2* __restrict__ ebuf, int e) {
    __shared__ int hist[NB];
    __shared__ int base_[NB];
    for (int i = threadIdx.x; i < NB; i += 1024) hist[i] = 0;
    __syncthreads();
    int b0 = blockIdx.x * EPB;
    int s_[16], d_[16];
#pragma unroll
    for (int j = 0; j < 16; ++j) {
        int i = b0 + j * 1024 + threadIdx.x;
        if (i < e) {
            s_[j] = src[i];
            d_[j] = dst[i];
            atomicAdd(&hist[d_[j] / NPB], 1);
        } else d_[j] = -1;
    }
    __syncthreads();
    for (int i = threadIdx.x; i < NB; i += 1024) {
        int hc = hist[i];
        base_[i] = hc ? atomicAdd(&bcur[i], hc) : 0;
        hist[i] = 0;    // reuse as local cursor
    }
    __syncthreads();
#pragma unroll
    for (int j = 0; j < 16; ++j) {
        if (d_[j] >= 0) {
            int bu = d_[j] / NPB;
            int r = atomicAdd(&hist[bu], 1);
            ebuf[base_[bu] + r] = make_int2(s_[j], d_[j]);
        }
    }
}

__launch_bounds__(256)
__global__ void k_bucket_csr(const int2* __restrict__ ebuf, const int* __restrict__ bptr,
                             int* __restrict__ rp, int* __restrict__ col,
                             float* __restrict__ dinv, int n) {
    int b  = blockIdx.x;
    int lo = b * NPB;
    if (lo >= n) return;
    int hi  = min(lo + NPB, n);
    int eb0 = bptr[b], ec = bptr[b + 1] - eb0;

    __shared__ int2 pairs[CAP];
    __shared__ int  hist[NPB];
    __shared__ int  excl[NPB + 1];
    for (int j = threadIdx.x; j < NPB; j += 256) hist[j] = 0;
    __syncthreads();
    for (int i = threadIdx.x; i < ec; i += 256) {
        int2 p = ebuf[eb0 + i];
        if (i < CAP) pairs[i] = p;
        atomicAdd(&hist[p.y - lo], 1);
    }
    __syncthreads();
    if (threadIdx.x == 0) {
        int acc = 0;
        for (int j = 0; j < NPB; ++j) { excl[j] = acc; acc += hist[j]; }
        excl[NPB] = acc;
    }
    __syncthreads();
    for (int j = threadIdx.x; j < hi - lo; j += 256) {
        rp[lo + j]   = eb0 + excl[j];
        dinv[lo + j] = rsqrtf((float)(hist[j] + 1));   // +1 self loop
    }
    if (hi == n && threadIdx.x == 0) rp[n] = eb0 + ec;
    __syncthreads();
    for (int j = threadIdx.x; j < NPB; j += 256) hist[j] = 0;  // reuse as cursor
    __syncthreads();
    for (int i = threadIdx.x; i < ec; i += 256) {
        int2 p  = (i < CAP) ? pairs[i] : ebuf[eb0 + i];
        int  li = p.y - lo;
        int  r  = atomicAdd(&hist[li], 1);
        col[eb0 + excl[li] + r] = p.x;
    }
}

// ---------- GEMM1: h[N,64](bf16) = x[N,500] @ W1 via bf16 MFMA, LDS-staged A ----------
__launch_bounds__(256)
__global__ void k_gemm1(const float* __restrict__ x, const unsigned short* __restrict__ w1t,
                        unsigned short* __restrict__ h, int n) {
    __shared__ unsigned short xs[4][32][40];   // 10 KB
    const int tid  = threadIdx.x;
    const int wave = tid >> 6;
    const int lane = tid & 63;
    const int quad = lane >> 4;
    const int l16  = lane & 15;
    const int rowb = blockIdx.x * 128 + wave * 32;

    const int srow = lane >> 3;
    const int skof = (lane & 7) * 4;

    f32x4 acc[2][4];
#pragma unroll
    for (int rt = 0; rt < 2; ++rt)
#pragma unroll
        for (int ct = 0; ct < 4; ++ct) acc[rt][ct] = (f32x4)0.f;

    for (int ks = 0; ks < 16; ++ks) {
        const int k0 = ks * 32;

        float4 tmp[4];
        if (ks < 15) {
#pragma unroll
            for (int u = 0; u < 4; ++u) {
                int grow = rowb + u * 8 + srow;
                tmp[u] = (grow < n) ? *(const float4*)&x[(size_t)grow * F_IN + k0 + skof]
                                    : make_float4(0.f, 0.f, 0.f, 0.f);
            }
        } else {
#pragma unroll
            for (int u = 0; u < 4; ++u) {
                int grow = rowb + u * 8 + srow;
                const float* p = &x[(size_t)grow * F_IN];
                float v0 = (grow < n && k0 + skof + 0 < F_IN) ? p[k0 + skof + 0] : 0.f;
                float v1 = (grow < n && k0 + skof + 1 < F_IN) ? p[k0 + skof + 1] : 0.f;
                float v2 = (grow < n && k0 + skof + 2 < F_IN) ? p[k0 + skof + 2] : 0.f;
                float v3 = (grow < n && k0 + skof + 3 < F_IN) ? p[k0 + skof + 3] : 0.f;
                tmp[u] = make_float4(v0, v1, v2, v3);
            }
        }
        bf16x8 bfrag[4];
#pragma unroll
        for (int ct = 0; ct < 4; ++ct)
            bfrag[ct] = *(const bf16x8*)&w1t[(ct * 16 + l16) * KPAD + k0 + quad * 8];

#pragma unroll
        for (int u = 0; u < 4; ++u) {
            unsigned int lo = (unsigned int)f2bf(tmp[u].x) | ((unsigned int)f2bf(tmp[u].y) << 16);
            unsigned int hi = (unsigned int)f2bf(tmp[u].z) | ((unsigned int)f2bf(tmp[u].w) << 16);
            *(uint2*)&xs[wave][u * 8 + srow][skof] = make_uint2(lo, hi);
        }
        __syncthreads();

        union { bf16x8 v; unsigned int u[4]; } af[2];
#pragma unroll
        for (int rt = 0; rt < 2; ++rt) {
            uint2 a = *(const uint2*)&xs[wave][rt * 16 + l16][quad * 8];
            uint2 b = *(const uint2*)&xs[wave][rt * 16 + l16][quad * 8 + 4];
            af[rt].u[0] = a.x; af[rt].u[1] = a.y; af[rt].u[2] = b.x; af[rt].u[3] = b.y;
        }
#pragma unroll
        for (int rt = 0; rt < 2; ++rt)
#pragma unroll
            for (int ct = 0; ct < 4; ++ct)
                acc[rt][ct] = __builtin_amdgcn_mfma_f32_16x16x32_bf16(
                    af[rt].v, bfrag[ct], acc[rt][ct], 0, 0, 0);
        __syncthreads();
    }

    // D layout: row = quad*4 + reg, col = lane&15 ; store bf16
#pragma unroll
    for (int rt = 0; rt < 2; ++rt) {
#pragma unroll
        for (int reg = 0; reg < 4; ++reg) {
            int grow = rowb + rt * 16 + quad * 4 + reg;
            if (grow < n) {
#pragma unroll
                for (int ct = 0; ct < 4; ++ct)
                    h[(size_t)grow * HIDDEN + ct * 16 + l16] = f2bf(acc[rt][ct][reg]);
            }
        }
    }
}

// ---------- aggregation: bf16 gather table, fp32 accumulate/output ----------
template <int F, bool RELU, bool LSM>
__global__ void k_agg(const unsigned short* __restrict__ h, const int* __restrict__ rp,
                      const int* __restrict__ col, const float* __restrict__ dinv,
                      const float* __restrict__ bias, float* __restrict__ out, int n) {
    int wid  = (blockIdx.x * blockDim.x + threadIdx.x) >> 6;
    int lane = threadIdx.x & 63;
    if (wid >= n) return;
    const bool act = lane < F;
    int beg = rp[wid], end = rp[wid + 1];
    float acc = 0.f;
    int e = beg;
    for (; e + 4 <= end; e += 4) {          // 4 gathers in flight
        int s0 = col[e], s1 = col[e + 1], s2 = col[e + 2], s3 = col[e + 3];
        unsigned short u0 = act ? h[(size_t)s0 * F + lane] : (unsigned short)0;
        unsigned short u1 = act ? h[(size_t)s1 * F + lane] : (unsigned short)0;
        unsigned short u2 = act ? h[(size_t)s2 * F + lane] : (unsigned short)0;
        unsigned short u3 = act ? h[(size_t)s3 * F + lane] : (unsigned short)0;
        float w0 = dinv[s0], w1 = dinv[s1], w2 = dinv[s2], w3 = dinv[s3];
        acc += w0 * bf2f(u0) + w1 * bf2f(u1) + w2 * bf2f(u2) + w3 * bf2f(u3);
    }
    for (; e < end; ++e) {
        int s0 = col[e];
        unsigned short u0 = act ? h[(size_t)s0 * F + lane] : (unsigned short)0;
        acc += dinv[s0] * bf2f(u0);
    }
    float di    = dinv[wid];
    float selfv = act ? bf2f(h[(size_t)wid * F + lane]) : 0.f;
    float r = di * acc + di * di * selfv + (act ? bias[lane] : 0.f);
    if (RELU) r = fmaxf(r, 0.f);
    if (LSM) {
        float v = act ? r : -INFINITY;
        float m = v;
        for (int off = 32; off; off >>= 1) m = fmaxf(m, __shfl_xor(m, off));
        float ex = act ? __expf(v - m) : 0.f;
        float s = ex;
        for (int off = 32; off; off >>= 1) s += __shfl_xor(s, off);
        if (act) out[(size_t)wid * F + lane] = v - m - __logf(s);
    } else {
        if (act) out[(size_t)wid * F + lane] = r;
    }
}

// ---------- GEMM2: h2[N,40](bf16) = a[N,64](fp32) @ W2[64,40] ----------
__launch_bounds__(256)
__global__ void k_gemm2(const float* __restrict__ a, const float* __restrict__ w,
                        unsigned short* __restrict__ out, int n) {
    __shared__ float ws[HIDDEN * N_CLASS];
    for (int idx = threadIdx.x; idx < HIDDEN * N_CLASS; idx += 256) ws[idx] = w[idx];
    __syncthreads();
    int idx = blockIdx.x * 256 + threadIdx.x;
    if (idx >= n * N_CLASS) return;
    int i = idx / N_CLASS, j = idx - i * N_CLASS;
    float s = 0.f;
#pragma unroll
    for (int k = 0; k < HIDDEN; k += 4) {
        float4 xv = *(const float4*)&a[(size_t)i * HIDDEN + k];
        s = fmaf(xv.x, ws[k * N_CLASS + j], s);
        s = fmaf(xv.y, ws[(k + 1) * N_CLASS + j], s);
        s = fmaf(xv.z, ws[(k + 2) * N_CLASS + j], s);
        s = fmaf(xv.w, ws[(k + 3) * N_CLASS + j], s);
    }
    out[idx] = f2bf(s);
}

extern "C" void kernel_launch(void* const* d_in, const int* in_sizes, int n_in,
                              void* d_out, int out_size, void* d_ws, size_t ws_size,
                              hipStream_t stream) {
    const float* x   = (const float*)d_in[0];
    const float* W1  = (const float*)d_in[1];
    const float* b1  = (const float*)d_in[2];
    const float* W2  = (const float*)d_in[3];
    const float* b2  = (const float*)d_in[4];
    const int*   ei  = (const int*)d_in[5];
    const int*   src = ei;
    const int*   dst = ei + N_EDGES;
    float*       out = (float*)d_out;

    char*  ws  = (char*)d_ws;
    size_t off = 0;
    auto alloc = [&](size_t bytes) -> void* {
        void* p = ws + off;
        off += (bytes + 255) & ~(size_t)255;
        return p;
    };
    int*            bcnt = (int*)alloc((size_t)NB * 4);
    int*            bptr = (int*)alloc((size_t)(NB + 1) * 4);
    int*            bcur = (int*)alloc((size_t)NB * 4);
    int*            rp   = (int*)alloc((size_t)(N_NODES + 1) * 4);
    int*            col  = (int*)alloc((size_t)N_EDGES * 4);
    float*          dinv = (float*)alloc((size_t)N_NODES * 4);
    unsigned short* w1t  = (unsigned short*)alloc((size_t)HIDDEN * KPAD * 2);
    unsigned short* h1   = (unsigned short*)alloc((size_t)N_NODES * HIDDEN * 2);  // bf16
    float*          h1a  = (float*)alloc((size_t)N_NODES * HIDDEN * 4);           // fp32
    int2*           ebuf = (int2*)h1a;            // alias: ebuf dead before agg1 writes h1a
    unsigned short* h2   = h1;                    // bf16, aliases h1 (dead after agg1)

    const int NBH = (N_EDGES + EPB - 1) / EPB;   // 98

    // CSR build (bucketed counting sort) + W1^T prep
    k_zero_int<<<(NB + 255) / 256, 256, 0, stream>>>(bcnt, NB);
    k_prep_w1t<<<(HIDDEN * KPAD + 255) / 256, 256, 0, stream>>>(W1, w1t);
    k_bhist<<<NBH, 1024, 0, stream>>>(dst, bcnt, N_EDGES);
    k_bscan<<<1, 1024, 0, stream>>>(bcnt, bptr, bcur);
    k_bfill<<<NBH, 1024, 0, stream>>>(src, dst, bcur, ebuf, N_EDGES);
    k_bucket_csr<<<NB, 256, 0, stream>>>(ebuf, bptr, rp, col, dinv, N_NODES);

    // layer 1
    k_gemm1<<<(N_NODES + 127) / 128, 256, 0, stream>>>(x, w1t, h1, N_NODES);
    k_agg<HIDDEN, true, false><<<(N_NODES + 3) / 4, 256, 0, stream>>>(h1, rp, col, dinv, b1, h1a, N_NODES);

    // layer 2 (+fused log_softmax)
    k_gemm2<<<(N_NODES * N_CLASS + 255) / 256, 256, 0, stream>>>(h1a, W2, h2, N_NODES);
    k_agg<N_CLASS, false, true><<<(N_NODES + 3) / 4, 256, 0, stream>>>(h2, rp, col, dinv, b2, out, N_NODES);
}

// Round 6
// 538.462 us; speedup vs baseline: 1.1413x; 1.1413x over previous
//
#include <hip/hip_runtime.h>
#include <math.h>

#define N_NODES 100000
#define N_EDGES 1600000
#define F_IN    500
#define HIDDEN  64
#define N_CLASS 40
#define KPAD    512

#define NB   2048      // dst buckets
#define NPB  49        // nodes per bucket (2048*49 = 100352 >= N)
#define EPB  16384     // edges per block in bhist/bfill
#define CAP  1536      // LDS pair capacity in k_bucket_csr

typedef __attribute__((ext_vector_type(4))) float f32x4;
typedef __attribute__((ext_vector_type(8))) __bf16 bf16x8;

__device__ __forceinline__ unsigned short f2bf(float f) {
    unsigned int u = __float_as_uint(f);
    u = (u + 0x7FFF + ((u >> 16) & 1)) >> 16;   // RNE
    return (unsigned short)u;
}
__device__ __forceinline__ float bfu_lo(unsigned int v) {   // low ushort -> float
    return __uint_as_float(v << 16);
}
__device__ __forceinline__ float bfu_hi(unsigned int v) {   // high ushort -> float
    return __uint_as_float(v & 0xFFFF0000u);
}

// ---------- utility ----------
__global__ void k_zero_int(int* p, int n) {
    int i = blockIdx.x * blockDim.x + threadIdx.x;
    if (i < n) p[i] = 0;
}

// W1t[n][k] = bf16(W1[k][n]), k zero-padded to 512
__global__ void k_prep_w1t(const float* __restrict__ w1, unsigned short* __restrict__ w1t) {
    int idx = blockIdx.x * blockDim.x + threadIdx.x;
    if (idx >= HIDDEN * KPAD) return;
    int n = idx >> 9, k = idx & (KPAD - 1);
    float v = (k < F_IN) ? w1[k * HIDDEN + n] : 0.f;
    w1t[idx] = f2bf(v);
}

// ---------- CSR build: bucketed counting sort ----------
__launch_bounds__(1024)
__global__ void k_bhist(const int* __restrict__ dst, int* __restrict__ bcnt, int e) {
    __shared__ int h[NB];
    for (int i = threadIdx.x; i < NB; i += 1024) h[i] = 0;
    __syncthreads();
    int base = blockIdx.x * EPB;
#pragma unroll
    for (int j = 0; j < 16; ++j) {
        int i = base + j * 1024 + threadIdx.x;
        if (i < e) atomicAdd(&h[dst[i] / NPB], 1);
    }
    __syncthreads();
    for (int i = threadIdx.x; i < NB; i += 1024)
        if (h[i]) atomicAdd(&bcnt[i], h[i]);
}

__launch_bounds__(1024)
__global__ void k_bscan(const int* __restrict__ bcnt, int* __restrict__ bptr,
                        int* __restrict__ bcur) {
    __shared__ int s[1024];
    int t = threadIdx.x;
    int a = bcnt[2 * t], b = bcnt[2 * t + 1];
    int v = a + b;
    s[t] = v;
    __syncthreads();
    for (int off = 1; off < 1024; off <<= 1) {
        int u = (t >= off) ? s[t - off] : 0;
        __syncthreads();
        s[t] += u;
        __syncthreads();
    }
    int excl = s[t] - v;
    bptr[2 * t] = excl;     bptr[2 * t + 1] = excl + a;
    bcur[2 * t] = excl;     bcur[2 * t + 1] = excl + a;
    if (t == 1023) bptr[NB] = s[1023];
}

__launch_bounds__(1024)
__global__ void k_bfill(const int* __restrict__ src, const int* __restrict__ dst,
                        int* __restrict__ bcur, int2* __restrict__ ebuf, int e) {
    __shared__ int hist[NB];
    __shared__ int base_[NB];
    for (int i = threadIdx.x; i < NB; i += 1024) hist[i] = 0;
    __syncthreads();
    int b0 = blockIdx.x * EPB;
    int s_[16], d_[16];
#pragma unroll
    for (int j = 0; j < 16; ++j) {
        int i = b0 + j * 1024 + threadIdx.x;
        if (i < e) {
            s_[j] = src[i];
            d_[j] = dst[i];
            atomicAdd(&hist[d_[j] / NPB], 1);
        } else d_[j] = -1;
    }
    __syncthreads();
    for (int i = threadIdx.x; i < NB; i += 1024) {
        int hc = hist[i];
        base_[i] = hc ? atomicAdd(&bcur[i], hc) : 0;
        hist[i] = 0;    // reuse as local cursor
    }
    __syncthreads();
#pragma unroll
    for (int j = 0; j < 16; ++j) {
        if (d_[j] >= 0) {
            int bu = d_[j] / NPB;
            int r = atomicAdd(&hist[bu], 1);
            ebuf[base_[bu] + r] = make_int2(s_[j], d_[j]);
        }
    }
}

__launch_bounds__(256)
__global__ void k_bucket_csr(const int2* __restrict__ ebuf, const int* __restrict__ bptr,
                             int* __restrict__ rp, int* __restrict__ col,
                             float* __restrict__ dinv, int n) {
    int b  = blockIdx.x;
    int lo = b * NPB;
    if (lo >= n) return;
    int hi  = min(lo + NPB, n);
    int eb0 = bptr[b], ec = bptr[b + 1] - eb0;

    __shared__ int2 pairs[CAP];
    __shared__ int  hist[NPB];
    __shared__ int  excl[NPB + 1];
    for (int j = threadIdx.x; j < NPB; j += 256) hist[j] = 0;
    __syncthreads();
    for (int i = threadIdx.x; i < ec; i += 256) {
        int2 p = ebuf[eb0 + i];
        if (i < CAP) pairs[i] = p;
        atomicAdd(&hist[p.y - lo], 1);
    }
    __syncthreads();
    if (threadIdx.x == 0) {
        int acc = 0;
        for (int j = 0; j < NPB; ++j) { excl[j] = acc; acc += hist[j]; }
        excl[NPB] = acc;
    }
    __syncthreads();
    for (int j = threadIdx.x; j < hi - lo; j += 256) {
        rp[lo + j]   = eb0 + excl[j];
        dinv[lo + j] = rsqrtf((float)(hist[j] + 1));   // +1 self loop
    }
    if (hi == n && threadIdx.x == 0) rp[n] = eb0 + ec;
    __syncthreads();
    for (int j = threadIdx.x; j < NPB; j += 256) hist[j] = 0;  // reuse as cursor
    __syncthreads();
    for (int i = threadIdx.x; i < ec; i += 256) {
        int2 p  = (i < CAP) ? pairs[i] : ebuf[eb0 + i];
        int  li = p.y - lo;
        int  r  = atomicAdd(&hist[li], 1);
        col[eb0 + excl[li] + r] = p.x;
    }
}

// ---------- GEMM1: hs[N,64](bf16, pre-scaled by dinv) = dinv * (x @ W1) ----------
__launch_bounds__(256)
__global__ void k_gemm1(const float* __restrict__ x, const unsigned short* __restrict__ w1t,
                        const float* __restrict__ dinv, unsigned short* __restrict__ hs, int n) {
    __shared__ unsigned short xs[4][32][40];   // 10 KB
    const int tid  = threadIdx.x;
    const int wave = tid >> 6;
    const int lane = tid & 63;
    const int quad = lane >> 4;
    const int l16  = lane & 15;
    const int rowb = blockIdx.x * 128 + wave * 32;

    const int srow = lane >> 3;
    const int skof = (lane & 7) * 4;

    f32x4 acc[2][4];
#pragma unroll
    for (int rt = 0; rt < 2; ++rt)
#pragma unroll
        for (int ct = 0; ct < 4; ++ct) acc[rt][ct] = (f32x4)0.f;

    for (int ks = 0; ks < 16; ++ks) {
        const int k0 = ks * 32;

        float4 tmp[4];
        if (ks < 15) {
#pragma unroll
            for (int u = 0; u < 4; ++u) {
                int grow = rowb + u * 8 + srow;
                tmp[u] = (grow < n) ? *(const float4*)&x[(size_t)grow * F_IN + k0 + skof]
                                    : make_float4(0.f, 0.f, 0.f, 0.f);
            }
        } else {
#pragma unroll
            for (int u = 0; u < 4; ++u) {
                int grow = rowb + u * 8 + srow;
                const float* p = &x[(size_t)grow * F_IN];
                float v0 = (grow < n && k0 + skof + 0 < F_IN) ? p[k0 + skof + 0] : 0.f;
                float v1 = (grow < n && k0 + skof + 1 < F_IN) ? p[k0 + skof + 1] : 0.f;
                float v2 = (grow < n && k0 + skof + 2 < F_IN) ? p[k0 + skof + 2] : 0.f;
                float v3 = (grow < n && k0 + skof + 3 < F_IN) ? p[k0 + skof + 3] : 0.f;
                tmp[u] = make_float4(v0, v1, v2, v3);
            }
        }
        bf16x8 bfrag[4];
#pragma unroll
        for (int ct = 0; ct < 4; ++ct)
            bfrag[ct] = *(const bf16x8*)&w1t[(ct * 16 + l16) * KPAD + k0 + quad * 8];

#pragma unroll
        for (int u = 0; u < 4; ++u) {
            unsigned int lo = (unsigned int)f2bf(tmp[u].x) | ((unsigned int)f2bf(tmp[u].y) << 16);
            unsigned int hi = (unsigned int)f2bf(tmp[u].z) | ((unsigned int)f2bf(tmp[u].w) << 16);
            *(uint2*)&xs[wave][u * 8 + srow][skof] = make_uint2(lo, hi);
        }
        __syncthreads();

        union { bf16x8 v; unsigned int u[4]; } af[2];
#pragma unroll
        for (int rt = 0; rt < 2; ++rt) {
            uint2 a = *(const uint2*)&xs[wave][rt * 16 + l16][quad * 8];
            uint2 b = *(const uint2*)&xs[wave][rt * 16 + l16][quad * 8 + 4];
            af[rt].u[0] = a.x; af[rt].u[1] = a.y; af[rt].u[2] = b.x; af[rt].u[3] = b.y;
        }
#pragma unroll
        for (int rt = 0; rt < 2; ++rt)
#pragma unroll
            for (int ct = 0; ct < 4; ++ct)
                acc[rt][ct] = __builtin_amdgcn_mfma_f32_16x16x32_bf16(
                    af[rt].v, bfrag[ct], acc[rt][ct], 0, 0, 0);
        __syncthreads();
    }

    // D layout: row = quad*4 + reg, col = lane&15 ; store bf16 * dinv[row]
#pragma unroll
    for (int rt = 0; rt < 2; ++rt) {
#pragma unroll
        for (int reg = 0; reg < 4; ++reg) {
            int grow = rowb + rt * 16 + quad * 4 + reg;
            if (grow < n) {
                float dv = dinv[grow];
#pragma unroll
                for (int ct = 0; ct < 4; ++ct)
                    hs[(size_t)grow * HIDDEN + ct * 16 + l16] = f2bf(dv * acc[rt][ct][reg]);
            }
        }
    }
}

// ---------- aggregation over pre-scaled bf16 table ----------
// out[i] = dinv[i] * (sum_e hs[col[e]] + hs[i]) + b  (+ReLU or +log_softmax)
// Packed gathers: each uint = 2 bf16 features; half-wave 0 -> edge e, half 1 -> e+1.
template <int F, bool RELU, bool LSM>
__global__ void k_agg(const unsigned int* __restrict__ hs, const int* __restrict__ rp,
                      const int* __restrict__ col, const float* __restrict__ dinv,
                      const float* __restrict__ bias, float* __restrict__ out, int n) {
    constexpr int PW = F / 2;      // uints per row (32 or 20)
    int wid  = (blockIdx.x * blockDim.x + threadIdx.x) >> 6;
    wid = __builtin_amdgcn_readfirstlane(wid);
    if (wid >= n) return;
    const int lane = threadIdx.x & 63;
    const int half = lane >> 5;
    const int p    = lane & 31;
    const bool act = p < PW;

    int beg = rp[wid], end = rp[wid + 1];
    float alo = 0.f, ahi = 0.f;
    int e = beg + half;
    for (; e + 6 < end; e += 8) {             // 8 edges/wave-iter, 4 gathers in flight
        int c0 = col[e], c1 = col[e + 2], c2 = col[e + 4], c3 = col[e + 6];
        unsigned v0 = act ? hs[(unsigned)c0 * PW + p] : 0u;
        unsigned v1 = act ? hs[(unsigned)c1 * PW + p] : 0u;
        unsigned v2 = act ? hs[(unsigned)c2 * PW + p] : 0u;
        unsigned v3 = act ? hs[(unsigned)c3 * PW + p] : 0u;
        alo += bfu_lo(v0) + bfu_lo(v1) + bfu_lo(v2) + bfu_lo(v3);
        ahi += bfu_hi(v0) + bfu_hi(v1) + bfu_hi(v2) + bfu_hi(v3);
    }
    for (; e < end; e += 2) {                 // per-lane predicated tail
        int c0 = col[e];
        unsigned v0 = act ? hs[(unsigned)c0 * PW + p] : 0u;
        alo += bfu_lo(v0);
        ahi += bfu_hi(v0);
    }
    // combine the two half-wave edge streams
    alo += __shfl_xor(alo, 32);
    ahi += __shfl_xor(ahi, 32);

    float di = dinv[wid];
    unsigned sv = act ? hs[(unsigned)wid * PW + p] : 0u;
    float2 bv = act ? *(const float2*)&bias[2 * p] : make_float2(0.f, 0.f);
    float rlo = di * (alo + bfu_lo(sv)) + bv.x;
    float rhi = di * (ahi + bfu_hi(sv)) + bv.y;
    if (RELU) { rlo = fmaxf(rlo, 0.f); rhi = fmaxf(rhi, 0.f); }
    if (LSM) {
        float m = act ? fmaxf(rlo, rhi) : -INFINITY;
#pragma unroll
        for (int off = 16; off; off >>= 1) m = fmaxf(m, __shfl_xor(m, off));
        float ex = act ? (__expf(rlo - m) + __expf(rhi - m)) : 0.f;
#pragma unroll
        for (int off = 16; off; off >>= 1) ex += __shfl_xor(ex, off);
        float lse = m + __logf(ex);
        rlo -= lse; rhi -= lse;
    }
    if (half == 0 && act)
        *(float2*)&out[(size_t)wid * F + 2 * p] = make_float2(rlo, rhi);
}

// ---------- GEMM2: h2s[N,40](bf16, pre-scaled) = dinv * (a[N,64] @ W2[64,40]) ----------
__launch_bounds__(256)
__global__ void k_gemm2(const float* __restrict__ a, const float* __restrict__ w,
                        const float* __restrict__ dinv, unsigned short* __restrict__ out, int n) {
    __shared__ float ws[HIDDEN * N_CLASS];
    for (int idx = threadIdx.x; idx < HIDDEN * N_CLASS; idx += 256) ws[idx] = w[idx];
    __syncthreads();
    int idx = blockIdx.x * 256 + threadIdx.x;
    if (idx >= n * N_CLASS) return;
    int i = idx / N_CLASS, j = idx - i * N_CLASS;
    float s = 0.f;
#pragma unroll
    for (int k = 0; k < HIDDEN; k += 4) {
        float4 xv = *(const float4*)&a[(size_t)i * HIDDEN + k];
        s = fmaf(xv.x, ws[k * N_CLASS + j], s);
        s = fmaf(xv.y, ws[(k + 1) * N_CLASS + j], s);
        s = fmaf(xv.z, ws[(k + 2) * N_CLASS + j], s);
        s = fmaf(xv.w, ws[(k + 3) * N_CLASS + j], s);
    }
    out[idx] = f2bf(dinv[i] * s);
}

extern "C" void kernel_launch(void* const* d_in, const int* in_sizes, int n_in,
                              void* d_out, int out_size, void* d_ws, size_t ws_size,
                              hipStream_t stream) {
    const float* x   = (const float*)d_in[0];
    const float* W1  = (const float*)d_in[1];
    const float* b1  = (const float*)d_in[2];
    const float* W2  = (const float*)d_in[3];
    const float* b2  = (const float*)d_in[4];
    const int*   ei  = (const int*)d_in[5];
    const int*   src = ei;
    const int*   dst = ei + N_EDGES;
    float*       out = (float*)d_out;

    char*  ws  = (char*)d_ws;
    size_t off = 0;
    auto alloc = [&](size_t bytes) -> void* {
        void* p = ws + off;
        off += (bytes + 255) & ~(size_t)255;
        return p;
    };
    int*            bcnt = (int*)alloc((size_t)NB * 4);
    int*            bptr = (int*)alloc((size_t)(NB + 1) * 4);
    int*            bcur = (int*)alloc((size_t)NB * 4);
    int*            rp   = (int*)alloc((size_t)(N_NODES + 1) * 4);
    int*            col  = (int*)alloc((size_t)N_EDGES * 4);
    float*          dinv = (float*)alloc((size_t)N_NODES * 4);
    unsigned short* w1t  = (unsigned short*)alloc((size_t)HIDDEN * KPAD * 2);
    unsigned short* h1s  = (unsigned short*)alloc((size_t)N_NODES * HIDDEN * 2);  // bf16, pre-scaled
    float*          h1a  = (float*)alloc((size_t)N_NODES * HIDDEN * 4);           // fp32
    int2*           ebuf = (int2*)h1a;            // alias: ebuf dead before agg1 writes h1a
    unsigned short* h2s  = h1s;                   // bf16, aliases h1s (dead after agg1)

    const int NBH = (N_EDGES + EPB - 1) / EPB;   // 98

    // CSR build (bucketed counting sort) + W1^T prep
    k_zero_int<<<(NB + 255) / 256, 256, 0, stream>>>(bcnt, NB);
    k_prep_w1t<<<(HIDDEN * KPAD + 255) / 256, 256, 0, stream>>>(W1, w1t);
    k_bhist<<<NBH, 1024, 0, stream>>>(dst, bcnt, N_EDGES);
    k_bscan<<<1, 1024, 0, stream>>>(bcnt, bptr, bcur);
    k_bfill<<<NBH, 1024, 0, stream>>>(src, dst, bcur, ebuf, N_EDGES);
    k_bucket_csr<<<NB, 256, 0, stream>>>(ebuf, bptr, rp, col, dinv, N_NODES);

    // layer 1
    k_gemm1<<<(N_NODES + 127) / 128, 256, 0, stream>>>(x, w1t, dinv, h1s, N_NODES);
    k_agg<HIDDEN, true, false><<<(N_NODES + 3) / 4, 256, 0, stream>>>(
        (const unsigned int*)h1s, rp, col, dinv, b1, h1a, N_NODES);

    // layer 2 (+fused log_softmax)
    k_gemm2<<<(N_NODES * N_CLASS + 255) / 256, 256, 0, stream>>>(h1a, W2, dinv, h2s, N_NODES);
    k_agg<N_CLASS, false, true><<<(N_NODES + 3) / 4, 256, 0, stream>>>(
        (const unsigned int*)h2s, rp, col, dinv, b2, out, N_NODES);
}